// Round 13
// baseline (186.936 us; speedup 1.0000x reference)
//
#include <hip/hip_runtime.h>
#include <hip/hip_bf16.h>
#include <math.h>

#define NNODES 50000
#define NEDGES 800000
#define NRANGE 6250          // NNODES / 8 (exact)
#define NC     64            // edge chunks
#define CHUNK_E (NEDGES / NC)   // 12500 exact
#define NSLICE 4
#define SLICE_E (CHUNK_E / NSLICE)  // 3125

using short8 = __attribute__((ext_vector_type(8))) short;
using f32x4  = __attribute__((ext_vector_type(4))) float;
typedef unsigned long long u64;

__device__ __forceinline__ short f2bf(float f) {
    __hip_bfloat16 h = __float2bfloat16(f);
    return *reinterpret_cast<short*>(&h);
}

// ---------------- fused prep: hist | cvt_x | cvt_weights (512-thread blocks) ----
// (r11; hist = LDS histogram + per-edge rank, no global atomics -- r6 lesson)

__global__ __launch_bounds__(512)
void prep_kernel(const float* __restrict__ x, __hip_bfloat16* __restrict__ xb,
                 const float* __restrict__ w0, const float* __restrict__ w1,
                 const float* __restrict__ w2, const float* __restrict__ w3,
                 const float* __restrict__ w4, const float* __restrict__ w5,
                 __hip_bfloat16* __restrict__ Wb,
                 const int* __restrict__ dst, unsigned int* __restrict__ partial,
                 unsigned char* __restrict__ rank8) {
    __shared__ unsigned int hist[NNODES / 4];   // 12500 u32 = 50KB
    int b = blockIdx.x;
    int tid = threadIdx.x;
    if (b < 64) {                          // hist chunk b
        int c = b;
        for (int i = tid; i < NNODES / 4; i += 512) hist[i] = 0;
        __syncthreads();
        int base = c * CHUNK_E;
        for (int e = base + tid; e < base + CHUNK_E; e += 512) {
            int d = dst[e];
            int sh = 8 * (d & 3);
            unsigned int old = atomicAdd(&hist[d >> 2], 1u << sh);
            rank8[e] = (unsigned char)((old >> sh) & 0xffu);
        }
        __syncthreads();
        unsigned int* outp = partial + (size_t)c * (NNODES / 4);
        for (int i = tid; i < NNODES / 4; i += 512) outp[i] = hist[i];
    } else if (b < 1627) {                 // cvt x: 800000 short8 items
        int i = (b - 64) * 512 + tid;
        if (i < 800000) {
            const float4* p = (const float4*)x + (size_t)i * 2;
            float4 a = p[0], c4 = p[1];
            short8 o;
            o[0] = f2bf(a.x); o[1] = f2bf(a.y); o[2] = f2bf(a.z); o[3] = f2bf(a.w);
            o[4] = f2bf(c4.x); o[5] = f2bf(c4.y); o[6] = f2bf(c4.z); o[7] = f2bf(c4.w);
            *reinterpret_cast<short8*>((short*)xb + (size_t)i * 8) = o;
        }
    } else {                               // cvt weights: 65536 elems
        int i = (b - 1627) * 512 + tid;
        const float* src; int off;
        if      (i < 16384) { src = w0; off = 0; }
        else if (i < 32768) { src = w1; off = 16384; }
        else if (i < 40960) { src = w2; off = 32768; }
        else if (i < 49152) { src = w3; off = 40960; }
        else if (i < 57344) { src = w4; off = 49152; }
        else                { src = w5; off = 57344; }
        Wb[i] = __float2bfloat16(src[i - off]);
    }
}

// ---------------- scan1: degrees + per-chunk bases (TRANSPOSED cbase4) ----------
// cbase4 layout [NC/4][N] u32 (4 chunk-bases packed per u32): fill's per-edge
// lookup becomes a 25KB L2-hot region per block (r12: [N][NC] bytes = one cache
// line per edge, ~25MB compulsory fetch). Writes stay coalesced across n.

__global__ __launch_bounds__(1024)
void scan1_kernel(const unsigned int* __restrict__ partial,
                  unsigned int* __restrict__ cbase4,   // [16][N] u32
                  int* __restrict__ excl, int* __restrict__ bsum) {
    __shared__ int sdata[1024];
    int tid = threadIdx.x;
    int n = blockIdx.x * 1024 + tid;
    int deg = 0;
    if (n < NNODES) {
        int sh = 8 * (n & 3);
        int idx = n >> 2;
        unsigned int packed = 0;
#pragma unroll 4
        for (int c = 0; c < NC; ++c) {
            unsigned int w = partial[(size_t)c * (NNODES / 4) + idx];
            unsigned int cc = (w >> sh) & 0xffu;
            packed |= ((unsigned int)(deg & 0xff)) << (8 * (c & 3));   // excl base
            deg += (int)cc;
            if ((c & 3) == 3) { cbase4[(size_t)(c >> 2) * NNODES + n] = packed; packed = 0; }
        }
    }
    sdata[tid] = deg;
    __syncthreads();
    for (int off = 1; off < 1024; off <<= 1) {
        int t = (tid >= off) ? sdata[tid - off] : 0;
        __syncthreads();
        sdata[tid] += t;
        __syncthreads();
    }
    if (n < NNODES) excl[n] = sdata[tid] - deg;
    if (tid == 1023) bsum[blockIdx.x] = sdata[1023];
}

__global__ __launch_bounds__(64)
void scan2_kernel(int* __restrict__ bsum, int nb) {
    int lane = threadIdx.x;
    int v = (lane < nb) ? bsum[lane] : 0;
    int incl = v;
    for (int off = 1; off < 64; off <<= 1) {
        int t = __shfl_up(incl, off);
        if (lane >= off) incl += t;
    }
    if (lane < nb) bsum[lane] = incl - v;   // exclusive
    if (lane == 63) bsum[nb] = incl;        // total
}

// ---------------- fill: pure-map CSR scatter, XCD-partitioned ----------------

__global__ __launch_bounds__(256)
void fill_kernel(const int* __restrict__ src, const int* __restrict__ dst,
                 const float* __restrict__ ew,
                 const int* __restrict__ excl, const int* __restrict__ bsum,
                 const unsigned int* __restrict__ cbase4,
                 const unsigned char* __restrict__ rank8,
                 u64* __restrict__ edges) {
    int b = blockIdx.x;
    int r = b & 7;
    int t = b >> 3;
    int c = t & (NC - 1);
    int s = t >> 6;
    int lo = r * NRANGE;
    int base = c * CHUNK_E + s * SLICE_E;
    int end = base + SLICE_E;
    const unsigned int* cb = cbase4 + (size_t)(c >> 2) * NNODES;
    int csh = 8 * (c & 3);
    for (int e = base + threadIdx.x; e < end; e += 256) {
        int d = dst[e];
        unsigned int dl = (unsigned int)(d - lo);
        if (dl < NRANGE) {
            int cbv = (int)((cb[d] >> csh) & 0xffu);
            int slot = excl[d] + bsum[d >> 10] + cbv + (int)rank8[e];
            u64 pack = ((u64)(unsigned int)__float_as_int(ew[e]) << 32) | (unsigned int)src[e];
            edges[slot] = pack;
        }
    }
}

// ---------------- gather core (r8-proven shape: 64 lanes/node, 8 chains) -------

__device__ __forceinline__ void gstep(u64 e, const unsigned int* __restrict__ Fb,
                                      int lane, float& ax, float& ay) {
    unsigned int v = Fb[(size_t)(unsigned int)e * 64 + lane];
    float w = __uint_as_float((unsigned int)(e >> 32));
    ax += __uint_as_float(v << 16) * w;
    ay += __uint_as_float(v & 0xffff0000u) * w;
}

__device__ __forceinline__ unsigned int gather_node(const unsigned int* __restrict__ Fb,
                                                    const u64* __restrict__ edges,
                                                    int beg, int end, int lane) {
    float ax[8], ay[8];
#pragma unroll
    for (int j = 0; j < 8; ++j) { ax[j] = 0.f; ay[j] = 0.f; }
    int s = beg;
    for (; s + 8 <= end; s += 8) {
        u64 e[8];
#pragma unroll
        for (int j = 0; j < 8; ++j) e[j] = __builtin_nontemporal_load(edges + s + j);
#pragma unroll
        for (int j = 0; j < 8; ++j) gstep(e[j], Fb, lane, ax[j], ay[j]);
    }
    if (s + 4 <= end) {
        u64 e[4];
#pragma unroll
        for (int j = 0; j < 4; ++j) e[j] = __builtin_nontemporal_load(edges + s + j);
#pragma unroll
        for (int j = 0; j < 4; ++j) gstep(e[j], Fb, lane, ax[j], ay[j]);
        s += 4;
    }
    if (s + 2 <= end) {
        u64 e0 = __builtin_nontemporal_load(edges + s);
        u64 e1 = __builtin_nontemporal_load(edges + s + 1);
        gstep(e0, Fb, lane, ax[0], ay[0]);
        gstep(e1, Fb, lane, ax[1], ay[1]);
        s += 2;
    }
    if (s < end) {
        u64 e0 = __builtin_nontemporal_load(edges + s);
        gstep(e0, Fb, lane, ax[0], ay[0]);
    }
#pragma unroll
    for (int j = 4; j < 8; ++j) { ax[j - 4] += ax[j]; ay[j - 4] += ay[j]; }
    float axs = (ax[0] + ax[1]) + (ax[2] + ax[3]);
    float ays = (ay[0] + ay[1]) + (ay[2] + ay[3]);
    float inv = 1.f / fmaxf((float)(end - beg), 1.f);
    unsigned int lo = (unsigned int)(unsigned short)f2bf(axs * inv);
    unsigned int hi = (unsigned int)(unsigned short)f2bf(ays * inv);
    return lo | (hi << 16);
}

// ---------------- fused gather+linear kernels (128-thread, 2-wave blocks) ------
// r12 lesson: 4-wave blocks paid a max-of-4 barrier tail + vmcnt drain (2.3 vs
// 3.0 TB/s). Now: 16 nodes/block, 2 waves x 8 nodes each, ONE 2-wave barrier,
// waves split the MFMA col-groups. a2 (x/h row) fragments hoisted ABOVE the
// gather so their fetch hides under phase A. smean u-dim padded 16->20.

#define SMW 20

__global__ __launch_bounds__(128)
void fused1_kernel(const unsigned int* __restrict__ Fb,    // xb as uints [N][64]
                   const __hip_bfloat16* __restrict__ xb,
                   const int* __restrict__ excl, const int* __restrict__ bsum,
                   const u64* __restrict__ edges,
                   const __hip_bfloat16* __restrict__ Wb,
                   const float* __restrict__ bias,         // [128]
                   __hip_bfloat16* __restrict__ outb,      // hb [N,128]
                   int E) {
    __shared__ unsigned int smean[4][16][SMW];
    int wid  = threadIdx.x >> 6;    // 0..1
    int lane = threadIdx.x & 63;
    int nodeBase = blockIdx.x * 16;
    int m  = lane & 15;
    int kq = lane >> 4;

    // hoist: own-node x fragments (independent of gather)
    short8 a2[4];
    const short* A2p = (const short*)xb + (size_t)(nodeBase + m) * 128 + kq * 8;
#pragma unroll
    for (int kk = 0; kk < 4; ++kk) a2[kk] = *(const short8*)(A2p + kk * 32);

    // phase A: 8 nodes per wave
    for (int q = 0; q < 8; ++q) {
        int nodeLocal = wid * 8 + q;
        int node = nodeBase + nodeLocal;
        int beg = excl[node] + bsum[node >> 10];
        int end = (node + 1 < NNODES) ? (excl[node + 1] + bsum[(node + 1) >> 10]) : E;
        beg = __builtin_amdgcn_readfirstlane(beg);
        end = __builtin_amdgcn_readfirstlane(end);
        unsigned int mv = gather_node(Fb, edges, beg, end, lane);
        smean[lane >> 4][nodeLocal][lane & 15] = mv;
    }
    __syncthreads();

    // phase B: wave wid handles col groups wid*4 .. wid*4+3
    short8 a1[4];
#pragma unroll
    for (int kk = 0; kk < 4; ++kk)
        a1[kk] = *(const short8*)((const short*)&smean[kk][m][kq * 4]);
    const short* Wrel  = (const short*)Wb;           // W1_rel
    const short* Wroot = (const short*)Wb + 16384;   // W1_root

#pragma unroll
    for (int cc = 0; cc < 4; ++cc) {
        int c = wid * 4 + cc;
        f32x4 acc = {0.f, 0.f, 0.f, 0.f};
        const short* b1p = Wrel  + (size_t)(c * 16 + m) * 128 + kq * 8;
        const short* b2p = Wroot + (size_t)(c * 16 + m) * 128 + kq * 8;
#pragma unroll
        for (int kk = 0; kk < 4; ++kk) {
            short8 bw1 = *(const short8*)(b1p + kk * 32);
            acc = __builtin_amdgcn_mfma_f32_16x16x32_bf16(a1[kk], bw1, acc, 0, 0, 0);
            short8 bw2 = *(const short8*)(b2p + kk * 32);
            acc = __builtin_amdgcn_mfma_f32_16x16x32_bf16(a2[kk], bw2, acc, 0, 0, 0);
        }
        int col = c * 16 + m;
        float b = bias[col];
#pragma unroll
        for (int i = 0; i < 4; ++i) {
            int gn = nodeBase + kq * 4 + i;
            float v = acc[i] + b;
            v = (v > 0.f) ? v : expm1f(v);
            outb[(size_t)gn * 128 + col] = __float2bfloat16(v);
        }
    }
}

__global__ __launch_bounds__(128)
void fused2_kernel(const unsigned int* __restrict__ Fb,    // hb as uints [N][64]
                   const __hip_bfloat16* __restrict__ hb,
                   const int* __restrict__ excl, const int* __restrict__ bsum,
                   const u64* __restrict__ edges,
                   const __hip_bfloat16* __restrict__ Wb,
                   const float* __restrict__ bmu, const float* __restrict__ blv,
                   float* __restrict__ out,                // mu@0, lv@N*64
                   int E) {
    __shared__ unsigned int smean[4][16][SMW];
    int wid  = threadIdx.x >> 6;
    int lane = threadIdx.x & 63;
    int nodeBase = blockIdx.x * 16;
    int m  = lane & 15;
    int kq = lane >> 4;

    short8 a2[4];
    const short* A2p = (const short*)hb + (size_t)(nodeBase + m) * 128 + kq * 8;
#pragma unroll
    for (int kk = 0; kk < 4; ++kk) a2[kk] = *(const short8*)(A2p + kk * 32);

    for (int q = 0; q < 8; ++q) {
        int nodeLocal = wid * 8 + q;
        int node = nodeBase + nodeLocal;
        int beg = excl[node] + bsum[node >> 10];
        int end = (node + 1 < NNODES) ? (excl[node + 1] + bsum[(node + 1) >> 10]) : E;
        beg = __builtin_amdgcn_readfirstlane(beg);
        end = __builtin_amdgcn_readfirstlane(end);
        unsigned int mv = gather_node(Fb, edges, beg, end, lane);
        smean[lane >> 4][nodeLocal][lane & 15] = mv;
    }
    __syncthreads();

    short8 a1[4];
#pragma unroll
    for (int kk = 0; kk < 4; ++kk)
        a1[kk] = *(const short8*)((const short*)&smean[kk][m][kq * 4]);
    const short* WmuR = (const short*)Wb + 32768;
    const short* WmuT = (const short*)Wb + 40960;
    const short* WlvR = (const short*)Wb + 49152;
    const short* WlvT = (const short*)Wb + 57344;

#pragma unroll
    for (int cc = 0; cc < 2; ++cc) {
        int c = wid * 2 + cc;                         // col group 0..3 (64 cols)
        f32x4 accMu = {0.f, 0.f, 0.f, 0.f};
        f32x4 accLv = {0.f, 0.f, 0.f, 0.f};
        size_t wrow = (size_t)(c * 16 + m) * 128 + kq * 8;
#pragma unroll
        for (int kk = 0; kk < 4; ++kk) {
            short8 bm1 = *(const short8*)(WmuR + wrow + kk * 32);
            accMu = __builtin_amdgcn_mfma_f32_16x16x32_bf16(a1[kk], bm1, accMu, 0, 0, 0);
            short8 bm2 = *(const short8*)(WmuT + wrow + kk * 32);
            accMu = __builtin_amdgcn_mfma_f32_16x16x32_bf16(a2[kk], bm2, accMu, 0, 0, 0);
            short8 bl1 = *(const short8*)(WlvR + wrow + kk * 32);
            accLv = __builtin_amdgcn_mfma_f32_16x16x32_bf16(a1[kk], bl1, accLv, 0, 0, 0);
            short8 bl2 = *(const short8*)(WlvT + wrow + kk * 32);
            accLv = __builtin_amdgcn_mfma_f32_16x16x32_bf16(a2[kk], bl2, accLv, 0, 0, 0);
        }
        int col = c * 16 + m;
        float bmv = bmu[col], blv_ = blv[col];
#pragma unroll
        for (int i = 0; i < 4; ++i) {
            int gn = nodeBase + kq * 4 + i;
            out[(size_t)gn * 64 + col] = accMu[i] + bmv;
            out[(size_t)NNODES * 64 + (size_t)gn * 64 + col] = accLv[i] + blv_;
        }
    }
}

extern "C" void kernel_launch(void* const* d_in, const int* in_sizes, int n_in,
                              void* d_out, int out_size, void* d_ws, size_t ws_size,
                              hipStream_t stream) {
    const float* x        = (const float*)d_in[0];
    const int*   eidx     = (const int*)d_in[1];
    const float* eattr    = (const float*)d_in[2];
    const float* W1_rel   = (const float*)d_in[3];
    const float* b1_rel   = (const float*)d_in[4];
    const float* W1_root  = (const float*)d_in[5];
    const float* Wmu_rel  = (const float*)d_in[6];
    const float* bmu_rel  = (const float*)d_in[7];
    const float* Wmu_root = (const float*)d_in[8];
    const float* Wlv_rel  = (const float*)d_in[9];
    const float* blv_rel  = (const float*)d_in[10];
    const float* Wlv_root = (const float*)d_in[11];
    float* out = (float*)d_out;

    const int N = NNODES, E = NEDGES;
    const int nb = (N + 1023) / 1024;   // 49
    const int* src = eidx;
    const int* dst = eidx + E;

    char* ws = (char*)d_ws;
    size_t off = 0;
    int* excl = (int*)(ws + off); off += (size_t)N * 4;
    int* bsum = (int*)(ws + off); off += 256;
    off = (off + 63) & ~(size_t)63;
    unsigned int* partial = (unsigned int*)(ws + off); off += (size_t)NC * (N / 4) * 4;  // 3.2MB
    unsigned int* cbase4  = (unsigned int*)(ws + off); off += (size_t)16 * N * 4;        // 3.2MB
    unsigned char* rank8  = (unsigned char*)(ws + off); off += (size_t)E;                // 0.8MB
    off = (off + 63) & ~(size_t)63;
    u64* edges = (u64*)(ws + off); off += (size_t)E * 8;
    __hip_bfloat16* xb    = (__hip_bfloat16*)(ws + off); off += (size_t)N * 128 * 2;
    __hip_bfloat16* hb    = (__hip_bfloat16*)(ws + off); off += (size_t)N * 128 * 2;
    __hip_bfloat16* Wb    = (__hip_bfloat16*)(ws + off); off += 65536 * 2;

    // fused prep: hist | cvt_x | cvt_weights
    prep_kernel<<<1755, 512, 0, stream>>>(x, xb, W1_rel, W1_root, Wmu_rel, Wmu_root,
                                          Wlv_rel, Wlv_root, Wb, dst, partial, rank8);
    scan1_kernel<<<nb, 1024, 0, stream>>>(partial, cbase4, excl, bsum);
    scan2_kernel<<<1, 64, 0, stream>>>(bsum, nb);
    fill_kernel<<<NC * 8 * NSLICE, 256, 0, stream>>>(src, dst, eattr, excl, bsum,
                                                     cbase4, rank8, edges);

    // layer 1: gather(xb) + linear1 fused -> hb
    fused1_kernel<<<N / 16, 128, 0, stream>>>(
        (const unsigned int*)xb, xb, excl, bsum, edges, Wb, b1_rel, hb, E);
    // layer 2: gather(hb) + linear2 fused -> out (mu, logvar)
    fused2_kernel<<<N / 16, 128, 0, stream>>>(
        (const unsigned int*)hb, hb, excl, bsum, edges, Wb, bmu_rel, blv_rel, out, E);
}

// Round 14
// 175.726 us; speedup vs baseline: 1.0638x; 1.0638x over previous
//
#include <hip/hip_runtime.h>
#include <hip/hip_bf16.h>
#include <math.h>

#define NNODES 50000
#define NEDGES 800000
#define NRANGE 6250          // NNODES / 8 (exact)
#define NC     64            // edge chunks
#define CHUNK_E (NEDGES / NC)   // 12500 exact
#define NSLICE 4
#define SLICE_E (CHUNK_E / NSLICE)  // 3125

using short8 = __attribute__((ext_vector_type(8))) short;
using f32x4  = __attribute__((ext_vector_type(4))) float;
typedef unsigned long long u64;

__device__ __forceinline__ short f2bf(float f) {
    __hip_bfloat16 h = __float2bfloat16(f);
    return *reinterpret_cast<short*>(&h);
}

// ---------------- fused prep: hist | cvt_x | cvt_weights (512-thread blocks) ----
// (r11; hist = LDS histogram + per-edge rank, no global atomics -- r6 lesson)

__global__ __launch_bounds__(512)
void prep_kernel(const float* __restrict__ x, __hip_bfloat16* __restrict__ xb,
                 const float* __restrict__ w0, const float* __restrict__ w1,
                 const float* __restrict__ w2, const float* __restrict__ w3,
                 const float* __restrict__ w4, const float* __restrict__ w5,
                 __hip_bfloat16* __restrict__ Wb,
                 const int* __restrict__ dst, unsigned int* __restrict__ partial,
                 unsigned char* __restrict__ rank8) {
    __shared__ unsigned int hist[NNODES / 4];   // 12500 u32 = 50KB
    int b = blockIdx.x;
    int tid = threadIdx.x;
    if (b < 64) {                          // hist chunk b
        int c = b;
        for (int i = tid; i < NNODES / 4; i += 512) hist[i] = 0;
        __syncthreads();
        int base = c * CHUNK_E;
        for (int e = base + tid; e < base + CHUNK_E; e += 512) {
            int d = dst[e];
            int sh = 8 * (d & 3);
            unsigned int old = atomicAdd(&hist[d >> 2], 1u << sh);
            rank8[e] = (unsigned char)((old >> sh) & 0xffu);
        }
        __syncthreads();
        unsigned int* outp = partial + (size_t)c * (NNODES / 4);
        for (int i = tid; i < NNODES / 4; i += 512) outp[i] = hist[i];
    } else if (b < 1627) {                 // cvt x: 800000 short8 items
        int i = (b - 64) * 512 + tid;
        if (i < 800000) {
            const float4* p = (const float4*)x + (size_t)i * 2;
            float4 a = p[0], c4 = p[1];
            short8 o;
            o[0] = f2bf(a.x); o[1] = f2bf(a.y); o[2] = f2bf(a.z); o[3] = f2bf(a.w);
            o[4] = f2bf(c4.x); o[5] = f2bf(c4.y); o[6] = f2bf(c4.z); o[7] = f2bf(c4.w);
            *reinterpret_cast<short8*>((short*)xb + (size_t)i * 8) = o;
        }
    } else {                               // cvt weights: 65536 elems
        int i = (b - 1627) * 512 + tid;
        const float* src; int off;
        if      (i < 16384) { src = w0; off = 0; }
        else if (i < 32768) { src = w1; off = 16384; }
        else if (i < 40960) { src = w2; off = 32768; }
        else if (i < 49152) { src = w3; off = 40960; }
        else if (i < 57344) { src = w4; off = 49152; }
        else                { src = w5; off = 57344; }
        Wb[i] = __float2bfloat16(src[i - off]);
    }
}

// ---------------- scan1: degrees + per-chunk bases (transposed cbase4) ----------

__global__ __launch_bounds__(1024)
void scan1_kernel(const unsigned int* __restrict__ partial,
                  unsigned int* __restrict__ cbase4,   // [16][N] u32
                  int* __restrict__ excl, int* __restrict__ bsum) {
    __shared__ int sdata[1024];
    int tid = threadIdx.x;
    int n = blockIdx.x * 1024 + tid;
    int deg = 0;
    if (n < NNODES) {
        int sh = 8 * (n & 3);
        int idx = n >> 2;
        unsigned int packed = 0;
#pragma unroll 4
        for (int c = 0; c < NC; ++c) {
            unsigned int w = partial[(size_t)c * (NNODES / 4) + idx];
            unsigned int cc = (w >> sh) & 0xffu;
            packed |= ((unsigned int)(deg & 0xff)) << (8 * (c & 3));   // excl base
            deg += (int)cc;
            if ((c & 3) == 3) { cbase4[(size_t)(c >> 2) * NNODES + n] = packed; packed = 0; }
        }
    }
    sdata[tid] = deg;
    __syncthreads();
    for (int off = 1; off < 1024; off <<= 1) {
        int t = (tid >= off) ? sdata[tid - off] : 0;
        __syncthreads();
        sdata[tid] += t;
        __syncthreads();
    }
    if (n < NNODES) excl[n] = sdata[tid] - deg;
    if (tid == 1023) bsum[blockIdx.x] = sdata[1023];
}

__global__ __launch_bounds__(64)
void scan2_kernel(int* __restrict__ bsum, int nb) {
    int lane = threadIdx.x;
    int v = (lane < nb) ? bsum[lane] : 0;
    int incl = v;
    for (int off = 1; off < 64; off <<= 1) {
        int t = __shfl_up(incl, off);
        if (lane >= off) incl += t;
    }
    if (lane < nb) bsum[lane] = incl - v;   // exclusive
    if (lane == 63) bsum[nb] = incl;        // total
}

// ---------------- fill: pure-map CSR scatter, XCD-partitioned ----------------

__global__ __launch_bounds__(256)
void fill_kernel(const int* __restrict__ src, const int* __restrict__ dst,
                 const float* __restrict__ ew,
                 const int* __restrict__ excl, const int* __restrict__ bsum,
                 const unsigned int* __restrict__ cbase4,
                 const unsigned char* __restrict__ rank8,
                 u64* __restrict__ edges) {
    int b = blockIdx.x;
    int r = b & 7;
    int t = b >> 3;
    int c = t & (NC - 1);
    int s = t >> 6;
    int lo = r * NRANGE;
    int base = c * CHUNK_E + s * SLICE_E;
    int end = base + SLICE_E;
    const unsigned int* cb = cbase4 + (size_t)(c >> 2) * NNODES;
    int csh = 8 * (c & 3);
    for (int e = base + threadIdx.x; e < end; e += 256) {
        int d = dst[e];
        unsigned int dl = (unsigned int)(d - lo);
        if (dl < NRANGE) {
            int cbv = (int)((cb[d] >> csh) & 0xffu);
            int slot = excl[d] + bsum[d >> 10] + cbv + (int)rank8[e];
            u64 pack = ((u64)(unsigned int)__float_as_int(ew[e]) << 32) | (unsigned int)src[e];
            edges[slot] = pack;
        }
    }
}

// ---------------- gather core (r8-proven shape: 64 lanes/node, 8 chains) -------

__device__ __forceinline__ void gstep(u64 e, const unsigned int* __restrict__ Fb,
                                      int lane, float& ax, float& ay) {
    unsigned int v = Fb[(size_t)(unsigned int)e * 64 + lane];
    float w = __uint_as_float((unsigned int)(e >> 32));
    ax += __uint_as_float(v << 16) * w;
    ay += __uint_as_float(v & 0xffff0000u) * w;
}

__device__ __forceinline__ unsigned int gather_node(const unsigned int* __restrict__ Fb,
                                                    const u64* __restrict__ edges,
                                                    int beg, int end, int lane) {
    float ax[8], ay[8];
#pragma unroll
    for (int j = 0; j < 8; ++j) { ax[j] = 0.f; ay[j] = 0.f; }
    int s = beg;
    for (; s + 8 <= end; s += 8) {
        u64 e[8];
#pragma unroll
        for (int j = 0; j < 8; ++j) e[j] = __builtin_nontemporal_load(edges + s + j);
#pragma unroll
        for (int j = 0; j < 8; ++j) gstep(e[j], Fb, lane, ax[j], ay[j]);
    }
    if (s + 4 <= end) {
        u64 e[4];
#pragma unroll
        for (int j = 0; j < 4; ++j) e[j] = __builtin_nontemporal_load(edges + s + j);
#pragma unroll
        for (int j = 0; j < 4; ++j) gstep(e[j], Fb, lane, ax[j], ay[j]);
        s += 4;
    }
    if (s + 2 <= end) {
        u64 e0 = __builtin_nontemporal_load(edges + s);
        u64 e1 = __builtin_nontemporal_load(edges + s + 1);
        gstep(e0, Fb, lane, ax[0], ay[0]);
        gstep(e1, Fb, lane, ax[1], ay[1]);
        s += 2;
    }
    if (s < end) {
        u64 e0 = __builtin_nontemporal_load(edges + s);
        gstep(e0, Fb, lane, ax[0], ay[0]);
    }
#pragma unroll
    for (int j = 4; j < 8; ++j) { ax[j - 4] += ax[j]; ay[j - 4] += ay[j]; }
    float axs = (ax[0] + ax[1]) + (ax[2] + ax[3]);
    float ays = (ay[0] + ay[1]) + (ay[2] + ay[3]);
    float inv = 1.f / fmaxf((float)(end - beg), 1.f);
    unsigned int lo = (unsigned int)(unsigned short)f2bf(axs * inv);
    unsigned int hi = (unsigned int)(unsigned short)f2bf(ays * inv);
    return lo | (hi << 16);
}

// ---------------- fused gather+linear kernels (r12 shape + work-stealing) ------
// r13 lesson: 128-thread blocks dropped occupancy 62->44% (workgroup-slot cap)
// and doubled each wave's serial node chain -> regression. Back to r12's 256t/
// 4-wave/16-node blocks. NEW: LDS work-stealing cursor replaces static 4-node-
// per-wave split -- the block's barrier tail becomes near-mean instead of
// max-of-4 degree sums. a2 (own-row) fragments hoisted above phase A (r13,
// kept). smean u-dim padded 16->20 for aligned b128 reads.

#define SMW 20

__global__ __launch_bounds__(256)
void fused1_kernel(const unsigned int* __restrict__ Fb,    // xb as uints [N][64]
                   const __hip_bfloat16* __restrict__ xb,
                   const int* __restrict__ excl, const int* __restrict__ bsum,
                   const u64* __restrict__ edges,
                   const __hip_bfloat16* __restrict__ Wb,
                   const float* __restrict__ bias,         // [128]
                   __hip_bfloat16* __restrict__ outb,      // hb [N,128]
                   int E) {
    __shared__ unsigned int smean[4][16][SMW];
    __shared__ int cursor;
    int lane = threadIdx.x & 63;
    int wid  = threadIdx.x >> 6;
    int nodeBase = blockIdx.x * 16;
    int m  = lane & 15;
    int kq = lane >> 4;

    if (threadIdx.x == 0) cursor = 0;

    // hoist: own-node x fragments (independent of gather)
    short8 a2[4];
    const short* A2p = (const short*)xb + (size_t)(nodeBase + m) * 128 + kq * 8;
#pragma unroll
    for (int kk = 0; kk < 4; ++kk) a2[kk] = *(const short8*)(A2p + kk * 32);
    __syncthreads();

    // phase A: work-stealing over the block's 16 nodes
    for (;;) {
        int nodeLocal;
        if (lane == 0) nodeLocal = atomicAdd(&cursor, 1);
        nodeLocal = __shfl(nodeLocal, 0);
        if (nodeLocal >= 16) break;
        int node = nodeBase + nodeLocal;
        int beg = excl[node] + bsum[node >> 10];
        int end = (node + 1 < NNODES) ? (excl[node + 1] + bsum[(node + 1) >> 10]) : E;
        beg = __builtin_amdgcn_readfirstlane(beg);
        end = __builtin_amdgcn_readfirstlane(end);
        unsigned int mv = gather_node(Fb, edges, beg, end, lane);
        smean[lane >> 4][nodeLocal][lane & 15] = mv;
    }
    __syncthreads();

    // phase B: wave wid handles col groups wid*2, wid*2+1
    short8 a1[4];
#pragma unroll
    for (int kk = 0; kk < 4; ++kk)
        a1[kk] = *(const short8*)((const short*)&smean[kk][m][kq * 4]);
    const short* Wrel  = (const short*)Wb;           // W1_rel
    const short* Wroot = (const short*)Wb + 16384;   // W1_root

#pragma unroll
    for (int cc = 0; cc < 2; ++cc) {
        int c = wid * 2 + cc;                         // col group 0..7
        f32x4 acc = {0.f, 0.f, 0.f, 0.f};
        const short* b1p = Wrel  + (size_t)(c * 16 + m) * 128 + kq * 8;
        const short* b2p = Wroot + (size_t)(c * 16 + m) * 128 + kq * 8;
#pragma unroll
        for (int kk = 0; kk < 4; ++kk) {
            short8 bw1 = *(const short8*)(b1p + kk * 32);
            acc = __builtin_amdgcn_mfma_f32_16x16x32_bf16(a1[kk], bw1, acc, 0, 0, 0);
            short8 bw2 = *(const short8*)(b2p + kk * 32);
            acc = __builtin_amdgcn_mfma_f32_16x16x32_bf16(a2[kk], bw2, acc, 0, 0, 0);
        }
        int col = c * 16 + m;
        float b = bias[col];
#pragma unroll
        for (int i = 0; i < 4; ++i) {
            int gn = nodeBase + kq * 4 + i;            // N % 16 == 0
            float v = acc[i] + b;
            v = (v > 0.f) ? v : expm1f(v);
            outb[(size_t)gn * 128 + col] = __float2bfloat16(v);
        }
    }
}

__global__ __launch_bounds__(256)
void fused2_kernel(const unsigned int* __restrict__ Fb,    // hb as uints [N][64]
                   const __hip_bfloat16* __restrict__ hb,
                   const int* __restrict__ excl, const int* __restrict__ bsum,
                   const u64* __restrict__ edges,
                   const __hip_bfloat16* __restrict__ Wb,
                   const float* __restrict__ bmu, const float* __restrict__ blv,
                   float* __restrict__ out,                // mu@0, lv@N*64
                   int E) {
    __shared__ unsigned int smean[4][16][SMW];
    __shared__ int cursor;
    int lane = threadIdx.x & 63;
    int wid  = threadIdx.x >> 6;
    int nodeBase = blockIdx.x * 16;
    int m  = lane & 15;
    int kq = lane >> 4;

    if (threadIdx.x == 0) cursor = 0;

    short8 a2[4];
    const short* A2p = (const short*)hb + (size_t)(nodeBase + m) * 128 + kq * 8;
#pragma unroll
    for (int kk = 0; kk < 4; ++kk) a2[kk] = *(const short8*)(A2p + kk * 32);
    __syncthreads();

    for (;;) {
        int nodeLocal;
        if (lane == 0) nodeLocal = atomicAdd(&cursor, 1);
        nodeLocal = __shfl(nodeLocal, 0);
        if (nodeLocal >= 16) break;
        int node = nodeBase + nodeLocal;
        int beg = excl[node] + bsum[node >> 10];
        int end = (node + 1 < NNODES) ? (excl[node + 1] + bsum[(node + 1) >> 10]) : E;
        beg = __builtin_amdgcn_readfirstlane(beg);
        end = __builtin_amdgcn_readfirstlane(end);
        unsigned int mv = gather_node(Fb, edges, beg, end, lane);
        smean[lane >> 4][nodeLocal][lane & 15] = mv;
    }
    __syncthreads();

    short8 a1[4];
#pragma unroll
    for (int kk = 0; kk < 4; ++kk)
        a1[kk] = *(const short8*)((const short*)&smean[kk][m][kq * 4]);
    const short* WmuR = (const short*)Wb + 32768;
    const short* WmuT = (const short*)Wb + 40960;
    const short* WlvR = (const short*)Wb + 49152;
    const short* WlvT = (const short*)Wb + 57344;

    int c = wid;                                      // col group 0..3 (64 cols)
    f32x4 accMu = {0.f, 0.f, 0.f, 0.f};
    f32x4 accLv = {0.f, 0.f, 0.f, 0.f};
    size_t wrow = (size_t)(c * 16 + m) * 128 + kq * 8;
#pragma unroll
    for (int kk = 0; kk < 4; ++kk) {
        short8 bm1 = *(const short8*)(WmuR + wrow + kk * 32);
        accMu = __builtin_amdgcn_mfma_f32_16x16x32_bf16(a1[kk], bm1, accMu, 0, 0, 0);
        short8 bm2 = *(const short8*)(WmuT + wrow + kk * 32);
        accMu = __builtin_amdgcn_mfma_f32_16x16x32_bf16(a2[kk], bm2, accMu, 0, 0, 0);
        short8 bl1 = *(const short8*)(WlvR + wrow + kk * 32);
        accLv = __builtin_amdgcn_mfma_f32_16x16x32_bf16(a1[kk], bl1, accLv, 0, 0, 0);
        short8 bl2 = *(const short8*)(WlvT + wrow + kk * 32);
        accLv = __builtin_amdgcn_mfma_f32_16x16x32_bf16(a2[kk], bl2, accLv, 0, 0, 0);
    }
    int col = c * 16 + m;
    float bmv = bmu[col], blv_ = blv[col];
#pragma unroll
    for (int i = 0; i < 4; ++i) {
        int gn = nodeBase + kq * 4 + i;
        out[(size_t)gn * 64 + col] = accMu[i] + bmv;
        out[(size_t)NNODES * 64 + (size_t)gn * 64 + col] = accLv[i] + blv_;
    }
}

extern "C" void kernel_launch(void* const* d_in, const int* in_sizes, int n_in,
                              void* d_out, int out_size, void* d_ws, size_t ws_size,
                              hipStream_t stream) {
    const float* x        = (const float*)d_in[0];
    const int*   eidx     = (const int*)d_in[1];
    const float* eattr    = (const float*)d_in[2];
    const float* W1_rel   = (const float*)d_in[3];
    const float* b1_rel   = (const float*)d_in[4];
    const float* W1_root  = (const float*)d_in[5];
    const float* Wmu_rel  = (const float*)d_in[6];
    const float* bmu_rel  = (const float*)d_in[7];
    const float* Wmu_root = (const float*)d_in[8];
    const float* Wlv_rel  = (const float*)d_in[9];
    const float* blv_rel  = (const float*)d_in[10];
    const float* Wlv_root = (const float*)d_in[11];
    float* out = (float*)d_out;

    const int N = NNODES, E = NEDGES;
    const int nb = (N + 1023) / 1024;   // 49
    const int* src = eidx;
    const int* dst = eidx + E;

    char* ws = (char*)d_ws;
    size_t off = 0;
    int* excl = (int*)(ws + off); off += (size_t)N * 4;
    int* bsum = (int*)(ws + off); off += 256;
    off = (off + 63) & ~(size_t)63;
    unsigned int* partial = (unsigned int*)(ws + off); off += (size_t)NC * (N / 4) * 4;  // 3.2MB
    unsigned int* cbase4  = (unsigned int*)(ws + off); off += (size_t)16 * N * 4;        // 3.2MB
    unsigned char* rank8  = (unsigned char*)(ws + off); off += (size_t)E;                // 0.8MB
    off = (off + 63) & ~(size_t)63;
    u64* edges = (u64*)(ws + off); off += (size_t)E * 8;
    __hip_bfloat16* xb    = (__hip_bfloat16*)(ws + off); off += (size_t)N * 128 * 2;
    __hip_bfloat16* hb    = (__hip_bfloat16*)(ws + off); off += (size_t)N * 128 * 2;
    __hip_bfloat16* Wb    = (__hip_bfloat16*)(ws + off); off += 65536 * 2;

    // fused prep: hist | cvt_x | cvt_weights
    prep_kernel<<<1755, 512, 0, stream>>>(x, xb, W1_rel, W1_root, Wmu_rel, Wmu_root,
                                          Wlv_rel, Wlv_root, Wb, dst, partial, rank8);
    scan1_kernel<<<nb, 1024, 0, stream>>>(partial, cbase4, excl, bsum);
    scan2_kernel<<<1, 64, 0, stream>>>(bsum, nb);
    fill_kernel<<<NC * 8 * NSLICE, 256, 0, stream>>>(src, dst, eattr, excl, bsum,
                                                     cbase4, rank8, edges);

    // layer 1: gather(xb) + linear1 fused -> hb
    fused1_kernel<<<N / 16, 256, 0, stream>>>(
        (const unsigned int*)xb, xb, excl, bsum, edges, Wb, b1_rel, hb, E);
    // layer 2: gather(hb) + linear2 fused -> out (mu, logvar)
    fused2_kernel<<<N / 16, 256, 0, stream>>>(
        (const unsigned int*)hb, hb, excl, bsum, edges, Wb, bmu_rel, blv_rel, out, E);
}